// Round 1
// baseline (1642.186 us; speedup 1.0000x reference)
//
#include <hip/hip_runtime.h>

#define N_NODES 100000
#define N_EDGES 1000000
#define C 128
#define NL 3
#define G 64
#define EPS 1e-5f
#define SLOPE 0.01f

// ---------------- preprocessing ----------------

__global__ __launch_bounds__(256) void hist_edges_k(const int* __restrict__ dst, int* __restrict__ cnt) {
  int i = blockIdx.x * 256 + threadIdx.x;
  if (i < N_EDGES) atomicAdd(&cnt[dst[i]], 1);
}

__global__ __launch_bounds__(256) void hist_graph_k(const int* __restrict__ batch, int* __restrict__ gcnt) {
  int i = blockIdx.x * 256 + threadIdx.x;
  if (i < N_NODES) atomicAdd(&gcnt[batch[i]], 1);
}

// single-block exclusive scan over cnt[N] -> row_ptr, cursor (copy)
__global__ __launch_bounds__(1024) void scan_k(const int* __restrict__ cnt, int* __restrict__ row_ptr,
                                               int* __restrict__ cursor) {
  __shared__ int part[1024];
  const int t = threadIdx.x;
  const int CHUNK = (N_NODES + 1023) / 1024;   // 98
  const int s = t * CHUNK;
  const int e = min(s + CHUNK, N_NODES);
  int sum = 0;
  for (int i = s; i < e; i++) sum += cnt[i];
  part[t] = sum;
  __syncthreads();
  for (int off = 1; off < 1024; off <<= 1) {
    int v = part[t];
    int add = (t >= off) ? part[t - off] : 0;
    __syncthreads();
    part[t] = v + add;
    __syncthreads();
  }
  int run = (t == 0) ? 0 : part[t - 1];
  for (int i = s; i < e; i++) {
    row_ptr[i] = run;
    cursor[i] = run;
    run += cnt[i];
  }
  if (t == 0) row_ptr[N_NODES] = part[1023];
}

__global__ __launch_bounds__(256) void dinv_k(const int* __restrict__ cnt, const int* __restrict__ gcnt,
                                              float* __restrict__ dinv, float* __restrict__ cntinv) {
  int i = blockIdx.x * 256 + threadIdx.x;
  if (i < N_NODES) dinv[i] = rsqrtf((float)cnt[i] + 1.0f);   // deg + self-loop
  if (i < G) cntinv[i] = 1.0f / fmaxf((float)gcnt[i], 1.0f);
}

__global__ __launch_bounds__(256) void scatter_k(const int* __restrict__ src, const int* __restrict__ dst,
                                                 int* __restrict__ cursor, int* __restrict__ src_s) {
  int i = blockIdx.x * 256 + threadIdx.x;
  if (i < N_EDGES) {
    int d = dst[i];
    int p = atomicAdd(&cursor[d], 1);
    src_s[p] = src[i];
  }
}

// ---------------- per-layer kernels ----------------

// Y[n] = dinv[n] * (X[n] @ W)   fp32, 32 rows/block, W k-tiled 32x128 in LDS
__global__ __launch_bounds__(256) void gemm_y_k(const float* __restrict__ X, const float* __restrict__ W,
                                                const float* __restrict__ dinv, float* __restrict__ Y) {
  __shared__ float xs[32 * C];   // 16 KB
  __shared__ float ws[32 * C];   // 16 KB (k-tile)
  const int tid = threadIdx.x;
  const int cg = tid & 31;    // cols cg*4 .. cg*4+3
  const int rs = tid >> 5;    // rows rs, rs+8, rs+16, rs+24
  const int row0 = blockIdx.x * 32;
  {
    const float4* X4 = (const float4*)(X + (size_t)row0 * C);
    float4* s4 = (float4*)xs;
#pragma unroll
    for (int i = 0; i < 4; i++) s4[tid + i * 256] = X4[tid + i * 256];
  }
  float4 acc[4];
#pragma unroll
  for (int r = 0; r < 4; r++) acc[r] = make_float4(0.f, 0.f, 0.f, 0.f);
  const float4* xs4 = (const float4*)xs;
  const float4* ws4 = (const float4*)ws;
#pragma unroll
  for (int kt = 0; kt < 4; kt++) {
    __syncthreads();
    {
      const float4* W4 = (const float4*)(W + (size_t)kt * 32 * C);
      float4* s4 = (float4*)ws;
#pragma unroll
      for (int i = 0; i < 4; i++) s4[tid + i * 256] = W4[tid + i * 256];
    }
    __syncthreads();
#pragma unroll
    for (int k4 = 0; k4 < 8; k4++) {
      float4 xv[4];
#pragma unroll
      for (int r = 0; r < 4; r++) xv[r] = xs4[(rs + 8 * r) * 32 + kt * 8 + k4];
#pragma unroll
      for (int j = 0; j < 4; j++) {
        float4 wv = ws4[(k4 * 4 + j) * 32 + cg];
#pragma unroll
        for (int r = 0; r < 4; r++) {
          float xsc = (j == 0) ? xv[r].x : (j == 1) ? xv[r].y : (j == 2) ? xv[r].z : xv[r].w;
          acc[r].x += xsc * wv.x;
          acc[r].y += xsc * wv.y;
          acc[r].z += xsc * wv.z;
          acc[r].w += xsc * wv.w;
        }
      }
    }
  }
#pragma unroll
  for (int r = 0; r < 4; r++) {
    const int row = row0 + rs + 8 * r;
    const float dn = dinv[row];
    float4 o = acc[r];
    o.x *= dn; o.y *= dn; o.z *= dn; o.w *= dn;
    ((float4*)Y)[(size_t)row * 32 + cg] = o;
  }
}

// out[n] = dinv[n]*(Y[n] + sum_{e in CSR[n]} Y[src_e]) + b    (32 lanes per node)
__global__ __launch_bounds__(256) void agg_k(const float* __restrict__ Y, const int* __restrict__ row_ptr,
                                             const int* __restrict__ src_s, const float* __restrict__ dinv,
                                             const float* __restrict__ bias, float* __restrict__ out) {
  const int sub = threadIdx.x >> 5;
  const int lane = threadIdx.x & 31;
  const int n = blockIdx.x * 8 + sub;   // grid is exact: 12500*8 = 100000
  const float4* Y4 = (const float4*)Y;
  float4 acc = Y4[(size_t)n * 32 + lane];
  const int e0 = row_ptr[n];
  const int e1 = row_ptr[n + 1];
  for (int e = e0; e < e1; e++) {
    const int s = src_s[e];
    const float4 v = Y4[(size_t)s * 32 + lane];
    acc.x += v.x; acc.y += v.y; acc.z += v.z; acc.w += v.w;
  }
  const float dn = dinv[n];
  const float4 bb = ((const float4*)bias)[lane];
  float4 o;
  o.x = acc.x * dn + bb.x;
  o.y = acc.y * dn + bb.y;
  o.z = acc.z * dn + bb.z;
  o.w = acc.w * dn + bb.w;
  ((float4*)out)[(size_t)n * 32 + lane] = o;
}

__device__ __forceinline__ void flush4(float* dst, int g, int lane, float4 a) {
  float* p = dst + g * C + lane * 4;
  atomicAdd(p + 0, a.x);
  atomicAdd(p + 1, a.y);
  atomicAdd(p + 2, a.z);
  atomicAdd(p + 3, a.w);
}

// segment-sum of A over sorted batch -> meansum[G][C]; 8 groups/block, 64 nodes/group
__global__ __launch_bounds__(256) void gn_meansum_k(const float* __restrict__ A, const int* __restrict__ batch,
                                                    float* __restrict__ meansum) {
  const int sub = threadIdx.x >> 5;
  const int lane = threadIdx.x & 31;
  const int n0 = (blockIdx.x * 8 + sub) * 64;
  if (n0 >= N_NODES) return;
  const int nend = min(n0 + 64, N_NODES);
  const float4* A4 = (const float4*)A;
  float4 acc = make_float4(0.f, 0.f, 0.f, 0.f);
  int curg = batch[n0];
  for (int n = n0; n < nend; n++) {
    const int g = batch[n];
    if (g != curg) {
      flush4(meansum, curg, lane, acc);
      acc = make_float4(0.f, 0.f, 0.f, 0.f);
      curg = g;
    }
    const float4 v = A4[(size_t)n * 32 + lane];
    acc.x += v.x; acc.y += v.y; acc.z += v.z; acc.w += v.w;
  }
  flush4(meansum, curg, lane, acc);
}

// A <- A - mean[g]*mean_scale (in place), accumulate varsum[G][C]
__global__ __launch_bounds__(256) void gn_center_var_k(float* __restrict__ A, const int* __restrict__ batch,
                                                       const float* __restrict__ meansum,
                                                       const float* __restrict__ cntinv,
                                                       const float* __restrict__ mscale,
                                                       float* __restrict__ varsum) {
  const int sub = threadIdx.x >> 5;
  const int lane = threadIdx.x & 31;
  const int n0 = (blockIdx.x * 8 + sub) * 64;
  if (n0 >= N_NODES) return;
  const int nend = min(n0 + 64, N_NODES);
  float4* A4 = (float4*)A;
  const float4* MS4 = (const float4*)meansum;
  const float4 ms = ((const float4*)mscale)[lane];
  int curg = batch[n0];
  float ci = cntinv[curg];
  float4 msum = MS4[curg * 32 + lane];
  float4 mval = make_float4(msum.x * ci * ms.x, msum.y * ci * ms.y, msum.z * ci * ms.z, msum.w * ci * ms.w);
  float4 acc = make_float4(0.f, 0.f, 0.f, 0.f);
  for (int n = n0; n < nend; n++) {
    const int g = batch[n];
    if (g != curg) {
      flush4(varsum, curg, lane, acc);
      acc = make_float4(0.f, 0.f, 0.f, 0.f);
      curg = g;
      ci = cntinv[g];
      msum = MS4[g * 32 + lane];
      mval = make_float4(msum.x * ci * ms.x, msum.y * ci * ms.y, msum.z * ci * ms.z, msum.w * ci * ms.w);
    }
    float4 v = A4[(size_t)n * 32 + lane];
    v.x -= mval.x; v.y -= mval.y; v.z -= mval.z; v.w -= mval.w;
    A4[(size_t)n * 32 + lane] = v;
    acc.x += v.x * v.x; acc.y += v.y * v.y; acc.z += v.z * v.z; acc.w += v.w * v.w;
  }
  flush4(varsum, curg, lane, acc);
}

// A <- leaky_relu(A * rsqrt(var+eps) * w + b) in place; optional copy to out2
__global__ __launch_bounds__(256) void gn_apply_k(float* __restrict__ A, const int* __restrict__ batch,
                                                  const float* __restrict__ varsum,
                                                  const float* __restrict__ cntinv,
                                                  const float* __restrict__ w, const float* __restrict__ bias,
                                                  float* __restrict__ out2) {
  const int idx = blockIdx.x * 256 + threadIdx.x;   // over N*32 float4, exact grid
  const int n = idx >> 5;
  const int lane = idx & 31;
  const int g = batch[n];
  const float ci = cntinv[g];
  const float4 vs = ((const float4*)varsum)[g * 32 + lane];
  const float4 wv = ((const float4*)w)[lane];
  const float4 bv = ((const float4*)bias)[lane];
  float4 v = ((const float4*)A)[idx];
  float r;
  r = rsqrtf(vs.x * ci + EPS); v.x = v.x * r * wv.x + bv.x; v.x = (v.x > 0.f) ? v.x : SLOPE * v.x;
  r = rsqrtf(vs.y * ci + EPS); v.y = v.y * r * wv.y + bv.y; v.y = (v.y > 0.f) ? v.y : SLOPE * v.y;
  r = rsqrtf(vs.z * ci + EPS); v.z = v.z * r * wv.z + bv.z; v.z = (v.z > 0.f) ? v.z : SLOPE * v.z;
  r = rsqrtf(vs.w * ci + EPS); v.w = v.w * r * wv.w + bv.w; v.w = (v.w > 0.f) ? v.w : SLOPE * v.w;
  ((float4*)A)[idx] = v;
  if (out2) ((float4*)out2)[idx] = v;
}

// ---------------- driver ----------------

extern "C" void kernel_launch(void* const* d_in, const int* in_sizes, int n_in,
                              void* d_out, int out_size, void* d_ws, size_t ws_size,
                              hipStream_t stream) {
  const float* x = (const float*)d_in[0];
  const int* ei = (const int*)d_in[1];
  const int* batch = (const int*)d_in[2];
  const float* W = (const float*)d_in[3];
  const float* b = (const float*)d_in[4];
  const float* gw = (const float*)d_in[5];
  const float* gb = (const float*)d_in[6];
  const float* gms = (const float*)d_in[7];
  float* out = (float*)d_out;

  const int* src = ei;
  const int* dst = ei + N_EDGES;

  // workspace layout (all chunks multiple-of-4 elements -> 16B aligned)
  float* y = (float*)d_ws;                          // N*C
  int* cnt = (int*)(y + (size_t)N_NODES * C);       // N
  int* row_ptr = cnt + N_NODES;                     // N+4
  int* cursor = row_ptr + N_NODES + 4;              // N
  int* src_s = cursor + N_NODES;                    // E
  int* gcnt = src_s + N_EDGES;                      // G
  float* dinv = (float*)(gcnt + G);                 // N
  float* cntinv = dinv + N_NODES;                   // G
  float* meansum = cntinv + G;                      // G*C
  float* varsum = meansum + G * C;                  // G*C

  hipMemsetAsync(cnt, 0, N_NODES * sizeof(int), stream);
  hipMemsetAsync(gcnt, 0, G * sizeof(int), stream);
  hist_edges_k<<<(N_EDGES + 255) / 256, 256, 0, stream>>>(dst, cnt);
  hist_graph_k<<<(N_NODES + 255) / 256, 256, 0, stream>>>(batch, gcnt);
  scan_k<<<1, 1024, 0, stream>>>(cnt, row_ptr, cursor);
  dinv_k<<<(N_NODES + 255) / 256, 256, 0, stream>>>(cnt, gcnt, dinv, cntinv);
  scatter_k<<<(N_EDGES + 255) / 256, 256, 0, stream>>>(src, dst, cursor, src_s);

  for (int l = 0; l < NL; l++) {
    const float* Xl = (l == 0) ? x : out + (size_t)N_NODES * C * l;  // previous history slot
    float* slot = out + (size_t)N_NODES * C * (1 + l);
    hipMemsetAsync(meansum, 0, 2 * G * C * sizeof(float), stream);   // meansum+varsum adjacent
    gemm_y_k<<<N_NODES / 32, 256, 0, stream>>>(Xl, W + (size_t)l * C * C, dinv, y);
    agg_k<<<N_NODES / 8, 256, 0, stream>>>(y, row_ptr, src_s, dinv, b + (size_t)l * C, slot);
    gn_meansum_k<<<(N_NODES + 511) / 512, 256, 0, stream>>>(slot, batch, meansum);
    gn_center_var_k<<<(N_NODES + 511) / 512, 256, 0, stream>>>(slot, batch, meansum, cntinv,
                                                               gms + (size_t)l * C, varsum);
    gn_apply_k<<<(N_NODES * 32) / 256, 256, 0, stream>>>(slot, batch, varsum, cntinv,
                                                         gw + (size_t)l * C, gb + (size_t)l * C,
                                                         (l == NL - 1) ? out : nullptr);
  }
}

// Round 2
// 1203.143 us; speedup vs baseline: 1.3649x; 1.3649x over previous
//
#include <hip/hip_runtime.h>

#define N_NODES 100000
#define N_EDGES 1000000
#define C 128
#define NL 3
#define G 64
#define EPS 1e-5f
#define SLOPE 0.01f

// ---------------- preprocessing ----------------

__global__ __launch_bounds__(256) void hist_edges_k(const int* __restrict__ dst, int* __restrict__ cnt) {
  int i = blockIdx.x * 256 + threadIdx.x;
  if (i < N_EDGES) atomicAdd(&cnt[dst[i]], 1);
}

// batch is sorted: per-graph counts via binary search, no atomics. 64 threads.
__global__ __launch_bounds__(64) void graph_cnt_k(const int* __restrict__ batch, float* __restrict__ cntinv) {
  const int g = threadIdx.x;
  if (g >= G) return;
  auto lb = [&](int key) {
    int lo = 0, hi = N_NODES;
    while (lo < hi) { int mid = (lo + hi) >> 1; if (batch[mid] < key) lo = mid + 1; else hi = mid; }
    return lo;
  };
  const int a = lb(g), b = lb(g + 1);
  cntinv[g] = 1.0f / fmaxf((float)(b - a), 1.0f);
}

// single-block exclusive scan over cnt[N] -> row_ptr, cursor (copy)
__global__ __launch_bounds__(1024) void scan_k(const int* __restrict__ cnt, int* __restrict__ row_ptr,
                                               int* __restrict__ cursor) {
  __shared__ int part[1024];
  const int t = threadIdx.x;
  const int CHUNK = (N_NODES + 1023) / 1024;   // 98
  const int s = t * CHUNK;
  const int e = min(s + CHUNK, N_NODES);
  int sum = 0;
  for (int i = s; i < e; i++) sum += cnt[i];
  part[t] = sum;
  __syncthreads();
  for (int off = 1; off < 1024; off <<= 1) {
    int v = part[t];
    int add = (t >= off) ? part[t - off] : 0;
    __syncthreads();
    part[t] = v + add;
    __syncthreads();
  }
  int run = (t == 0) ? 0 : part[t - 1];
  for (int i = s; i < e; i++) {
    row_ptr[i] = run;
    cursor[i] = run;
    run += cnt[i];
  }
  if (t == 0) row_ptr[N_NODES] = part[1023];
}

__global__ __launch_bounds__(256) void dinv_k(const int* __restrict__ cnt, float* __restrict__ dinv) {
  int i = blockIdx.x * 256 + threadIdx.x;
  if (i < N_NODES) dinv[i] = rsqrtf((float)cnt[i] + 1.0f);   // deg + self-loop
}

__global__ __launch_bounds__(256) void scatter_k(const int* __restrict__ src, const int* __restrict__ dst,
                                                 int* __restrict__ cursor, int* __restrict__ src_s) {
  int i = blockIdx.x * 256 + threadIdx.x;
  if (i < N_EDGES) {
    int d = dst[i];
    int p = atomicAdd(&cursor[d], 1);
    src_s[p] = src[i];
  }
}

// ---------------- per-layer kernels ----------------

// Y[n] = dinv[n] * (X[n] @ W)   fp32, 32 rows/block, W k-tiled 32x128 in LDS
__global__ __launch_bounds__(256) void gemm_y_k(const float* __restrict__ X, const float* __restrict__ W,
                                                const float* __restrict__ dinv, float* __restrict__ Y) {
  __shared__ float xs[32 * C];   // 16 KB
  __shared__ float ws[32 * C];   // 16 KB (k-tile)
  const int tid = threadIdx.x;
  const int cg = tid & 31;    // cols cg*4 .. cg*4+3
  const int rs = tid >> 5;    // rows rs, rs+8, rs+16, rs+24
  const int row0 = blockIdx.x * 32;
  {
    const float4* X4 = (const float4*)(X + (size_t)row0 * C);
    float4* s4 = (float4*)xs;
#pragma unroll
    for (int i = 0; i < 4; i++) s4[tid + i * 256] = X4[tid + i * 256];
  }
  float4 acc[4];
#pragma unroll
  for (int r = 0; r < 4; r++) acc[r] = make_float4(0.f, 0.f, 0.f, 0.f);
  const float4* xs4 = (const float4*)xs;
  const float4* ws4 = (const float4*)ws;
#pragma unroll
  for (int kt = 0; kt < 4; kt++) {
    __syncthreads();
    {
      const float4* W4 = (const float4*)(W + (size_t)kt * 32 * C);
      float4* s4 = (float4*)ws;
#pragma unroll
      for (int i = 0; i < 4; i++) s4[tid + i * 256] = W4[tid + i * 256];
    }
    __syncthreads();
#pragma unroll
    for (int k4 = 0; k4 < 8; k4++) {
      float4 xv[4];
#pragma unroll
      for (int r = 0; r < 4; r++) xv[r] = xs4[(rs + 8 * r) * 32 + kt * 8 + k4];
#pragma unroll
      for (int j = 0; j < 4; j++) {
        float4 wv = ws4[(k4 * 4 + j) * 32 + cg];
#pragma unroll
        for (int r = 0; r < 4; r++) {
          float xsc = (j == 0) ? xv[r].x : (j == 1) ? xv[r].y : (j == 2) ? xv[r].z : xv[r].w;
          acc[r].x += xsc * wv.x;
          acc[r].y += xsc * wv.y;
          acc[r].z += xsc * wv.z;
          acc[r].w += xsc * wv.w;
        }
      }
    }
  }
#pragma unroll
  for (int r = 0; r < 4; r++) {
    const int row = row0 + rs + 8 * r;
    const float dn = dinv[row];
    float4 o = acc[r];
    o.x *= dn; o.y *= dn; o.z *= dn; o.w *= dn;
    ((float4*)Y)[(size_t)row * 32 + cg] = o;
  }
}

// out[n] = dinv[n]*(Y[n] + sum_{e in CSR[n]} Y[src_e]) + b    (32 lanes per node)
__global__ __launch_bounds__(256) void agg_k(const float* __restrict__ Y, const int* __restrict__ row_ptr,
                                             const int* __restrict__ src_s, const float* __restrict__ dinv,
                                             const float* __restrict__ bias, float* __restrict__ out) {
  const int sub = threadIdx.x >> 5;
  const int lane = threadIdx.x & 31;
  const int n = blockIdx.x * 8 + sub;   // grid is exact: 12500*8 = 100000
  const float4* Y4 = (const float4*)Y;
  float4 acc = Y4[(size_t)n * 32 + lane];
  const int e0 = row_ptr[n];
  const int e1 = row_ptr[n + 1];
  for (int e = e0; e < e1; e++) {
    const int s = src_s[e];
    const float4 v = Y4[(size_t)s * 32 + lane];
    acc.x += v.x; acc.y += v.y; acc.z += v.z; acc.w += v.w;
  }
  const float dn = dinv[n];
  const float4 bb = ((const float4*)bias)[lane];
  float4 o;
  o.x = acc.x * dn + bb.x;
  o.y = acc.y * dn + bb.y;
  o.z = acc.z * dn + bb.z;
  o.w = acc.w * dn + bb.w;
  ((float4*)out)[(size_t)n * 32 + lane] = o;
}

__device__ __forceinline__ void flush4(float* dst, int g, int lane, float4 a) {
  float* p = dst + g * C + lane * 4;
  atomicAdd(p + 0, a.x);
  atomicAdd(p + 1, a.y);
  atomicAdd(p + 2, a.z);
  atomicAdd(p + 3, a.w);
}

// segment-sum of A over sorted batch -> meansum[G][C]; 8 groups/block, 64 nodes/group
__global__ __launch_bounds__(256) void gn_meansum_k(const float* __restrict__ A, const int* __restrict__ batch,
                                                    float* __restrict__ meansum) {
  const int sub = threadIdx.x >> 5;
  const int lane = threadIdx.x & 31;
  const int n0 = (blockIdx.x * 8 + sub) * 64;
  if (n0 >= N_NODES) return;
  const int nend = min(n0 + 64, N_NODES);
  const float4* A4 = (const float4*)A;
  float4 acc = make_float4(0.f, 0.f, 0.f, 0.f);
  int curg = batch[n0];
  for (int n = n0; n < nend; n++) {
    const int g = batch[n];
    if (g != curg) {
      flush4(meansum, curg, lane, acc);
      acc = make_float4(0.f, 0.f, 0.f, 0.f);
      curg = g;
    }
    const float4 v = A4[(size_t)n * 32 + lane];
    acc.x += v.x; acc.y += v.y; acc.z += v.z; acc.w += v.w;
  }
  flush4(meansum, curg, lane, acc);
}

// A <- A - mean[g]*mean_scale (in place), accumulate varsum[G][C]
__global__ __launch_bounds__(256) void gn_center_var_k(float* __restrict__ A, const int* __restrict__ batch,
                                                       const float* __restrict__ meansum,
                                                       const float* __restrict__ cntinv,
                                                       const float* __restrict__ mscale,
                                                       float* __restrict__ varsum) {
  const int sub = threadIdx.x >> 5;
  const int lane = threadIdx.x & 31;
  const int n0 = (blockIdx.x * 8 + sub) * 64;
  if (n0 >= N_NODES) return;
  const int nend = min(n0 + 64, N_NODES);
  float4* A4 = (float4*)A;
  const float4* MS4 = (const float4*)meansum;
  const float4 ms = ((const float4*)mscale)[lane];
  int curg = batch[n0];
  float ci = cntinv[curg];
  float4 msum = MS4[curg * 32 + lane];
  float4 mval = make_float4(msum.x * ci * ms.x, msum.y * ci * ms.y, msum.z * ci * ms.z, msum.w * ci * ms.w);
  float4 acc = make_float4(0.f, 0.f, 0.f, 0.f);
  for (int n = n0; n < nend; n++) {
    const int g = batch[n];
    if (g != curg) {
      flush4(varsum, curg, lane, acc);
      acc = make_float4(0.f, 0.f, 0.f, 0.f);
      curg = g;
      ci = cntinv[g];
      msum = MS4[g * 32 + lane];
      mval = make_float4(msum.x * ci * ms.x, msum.y * ci * ms.y, msum.z * ci * ms.z, msum.w * ci * ms.w);
    }
    float4 v = A4[(size_t)n * 32 + lane];
    v.x -= mval.x; v.y -= mval.y; v.z -= mval.z; v.w -= mval.w;
    A4[(size_t)n * 32 + lane] = v;
    acc.x += v.x * v.x; acc.y += v.y * v.y; acc.z += v.z * v.z; acc.w += v.w * v.w;
  }
  flush4(varsum, curg, lane, acc);
}

// A <- leaky_relu(A * rsqrt(var+eps) * w + b) in place; optional copy to out2
__global__ __launch_bounds__(256) void gn_apply_k(float* __restrict__ A, const int* __restrict__ batch,
                                                  const float* __restrict__ varsum,
                                                  const float* __restrict__ cntinv,
                                                  const float* __restrict__ w, const float* __restrict__ bias,
                                                  float* __restrict__ out2) {
  const int idx = blockIdx.x * 256 + threadIdx.x;   // over N*32 float4, exact grid
  const int n = idx >> 5;
  const int lane = idx & 31;
  const int g = batch[n];
  const float ci = cntinv[g];
  const float4 vs = ((const float4*)varsum)[g * 32 + lane];
  const float4 wv = ((const float4*)w)[lane];
  const float4 bv = ((const float4*)bias)[lane];
  float4 v = ((const float4*)A)[idx];
  float r;
  r = rsqrtf(vs.x * ci + EPS); v.x = v.x * r * wv.x + bv.x; v.x = (v.x > 0.f) ? v.x : SLOPE * v.x;
  r = rsqrtf(vs.y * ci + EPS); v.y = v.y * r * wv.y + bv.y; v.y = (v.y > 0.f) ? v.y : SLOPE * v.y;
  r = rsqrtf(vs.z * ci + EPS); v.z = v.z * r * wv.z + bv.z; v.z = (v.z > 0.f) ? v.z : SLOPE * v.z;
  r = rsqrtf(vs.w * ci + EPS); v.w = v.w * r * wv.w + bv.w; v.w = (v.w > 0.f) ? v.w : SLOPE * v.w;
  ((float4*)A)[idx] = v;
  if (out2) ((float4*)out2)[idx] = v;
}

// ---------------- driver ----------------

extern "C" void kernel_launch(void* const* d_in, const int* in_sizes, int n_in,
                              void* d_out, int out_size, void* d_ws, size_t ws_size,
                              hipStream_t stream) {
  const float* x = (const float*)d_in[0];
  const int* ei = (const int*)d_in[1];
  const int* batch = (const int*)d_in[2];
  const float* W = (const float*)d_in[3];
  const float* b = (const float*)d_in[4];
  const float* gw = (const float*)d_in[5];
  const float* gb = (const float*)d_in[6];
  const float* gms = (const float*)d_in[7];
  float* out = (float*)d_out;

  const int* src = ei;
  const int* dst = ei + N_EDGES;

  // workspace layout (all chunks multiple-of-4 elements -> 16B aligned)
  float* y = (float*)d_ws;                          // N*C
  int* cnt = (int*)(y + (size_t)N_NODES * C);       // N
  int* row_ptr = cnt + N_NODES;                     // N+4
  int* cursor = row_ptr + N_NODES + 4;              // N
  int* src_s = cursor + N_NODES;                    // E
  float* dinv = (float*)(src_s + N_EDGES);          // N
  float* cntinv = dinv + N_NODES;                   // G
  float* meansum = cntinv + G;                      // G*C
  float* varsum = meansum + G * C;                  // G*C

  hipMemsetAsync(cnt, 0, N_NODES * sizeof(int), stream);
  hist_edges_k<<<(N_EDGES + 255) / 256, 256, 0, stream>>>(dst, cnt);
  graph_cnt_k<<<1, 64, 0, stream>>>(batch, cntinv);
  scan_k<<<1, 1024, 0, stream>>>(cnt, row_ptr, cursor);
  dinv_k<<<(N_NODES + 255) / 256, 256, 0, stream>>>(cnt, dinv);
  scatter_k<<<(N_EDGES + 255) / 256, 256, 0, stream>>>(src, dst, cursor, src_s);

  for (int l = 0; l < NL; l++) {
    const float* Xl = (l == 0) ? x : out + (size_t)N_NODES * C * l;  // previous history slot
    float* slot = out + (size_t)N_NODES * C * (1 + l);
    hipMemsetAsync(meansum, 0, 2 * G * C * sizeof(float), stream);   // meansum+varsum adjacent
    gemm_y_k<<<N_NODES / 32, 256, 0, stream>>>(Xl, W + (size_t)l * C * C, dinv, y);
    agg_k<<<N_NODES / 8, 256, 0, stream>>>(y, row_ptr, src_s, dinv, b + (size_t)l * C, slot);
    gn_meansum_k<<<(N_NODES + 511) / 512, 256, 0, stream>>>(slot, batch, meansum);
    gn_center_var_k<<<(N_NODES + 511) / 512, 256, 0, stream>>>(slot, batch, meansum, cntinv,
                                                               gms + (size_t)l * C, varsum);
    gn_apply_k<<<(N_NODES * 32) / 256, 256, 0, stream>>>(slot, batch, varsum, cntinv,
                                                         gw + (size_t)l * C, gb + (size_t)l * C,
                                                         (l == NL - 1) ? out : nullptr);
  }
}

// Round 3
// 987.732 us; speedup vs baseline: 1.6626x; 1.2181x over previous
//
#include <hip/hip_runtime.h>

#define N_NODES 100000
#define N_EDGES 1000000
#define C 128
#define NL 3
#define G 64
#define EPS 1e-5f
#define SLOPE 0.01f

#define SCAN_CH 392
#define SCAN_BLOCKS 256   // ceil(100000/392) == 256 exactly

// ---------------- preprocessing ----------------

__global__ __launch_bounds__(256) void hist_edges_k(const int* __restrict__ dst, int* __restrict__ cnt) {
  int i = blockIdx.x * 256 + threadIdx.x;
  if (i < N_EDGES) atomicAdd(&cnt[dst[i]], 1);
}

// batch is sorted: per-graph counts via binary search, no atomics. 64 threads.
__global__ __launch_bounds__(64) void graph_cnt_k(const int* __restrict__ batch, float* __restrict__ cntinv) {
  const int g = threadIdx.x;
  if (g >= G) return;
  auto lb = [&](int key) {
    int lo = 0, hi = N_NODES;
    while (lo < hi) { int mid = (lo + hi) >> 1; if (batch[mid] < key) lo = mid + 1; else hi = mid; }
    return lo;
  };
  const int a = lb(g), b = lb(g + 1);
  cntinv[g] = 1.0f / fmaxf((float)(b - a), 1.0f);
}

// multi-block scan, phase 1: per-chunk sums (coalesced)
__global__ __launch_bounds__(256) void scan1_k(const int* __restrict__ cnt, int* __restrict__ bsum) {
  __shared__ int red[256];
  const int b = blockIdx.x, t = threadIdx.x;
  const int s = b * SCAN_CH;
  const int e = min(s + SCAN_CH, N_NODES);
  int sum = 0;
  for (int i = s + t; i < e; i += 256) sum += cnt[i];
  red[t] = sum;
  __syncthreads();
  for (int off = 128; off > 0; off >>= 1) {
    if (t < off) red[t] += red[t + off];
    __syncthreads();
  }
  if (t == 0) bsum[b] = red[0];
}

// phase 2: exclusive scan of 256 block sums (one block)
__global__ __launch_bounds__(256) void scan2_k(const int* __restrict__ bsum, int* __restrict__ boff,
                                               int* __restrict__ row_ptr) {
  __shared__ int sh[256];
  const int t = threadIdx.x;
  sh[t] = bsum[t];
  __syncthreads();
  for (int off = 1; off < 256; off <<= 1) {
    int v = sh[t];
    int add = (t >= off) ? sh[t - off] : 0;
    __syncthreads();
    sh[t] = v + add;
    __syncthreads();
  }
  boff[t] = t ? sh[t - 1] : 0;
  if (t == 255) row_ptr[N_NODES] = sh[255];
}

// phase 3: per-chunk exclusive scan + global offset -> row_ptr, cursor
__global__ __launch_bounds__(256) void scan3_k(const int* __restrict__ cnt, const int* __restrict__ boff,
                                               int* __restrict__ row_ptr, int* __restrict__ cursor) {
  __shared__ int vals[SCAN_CH];
  __shared__ int tsum[256];
  const int b = blockIdx.x, t = threadIdx.x;
  const int s = b * SCAN_CH;
  const int e = min(s + SCAN_CH, N_NODES);
  const int len = e - s;
  for (int i = t; i < len; i += 256) vals[i] = cnt[s + i];
  __syncthreads();
  const int i0 = 2 * t, i1 = 2 * t + 1;
  const int a = (i0 < len) ? vals[i0] : 0;
  const int bb = (i1 < len) ? vals[i1] : 0;
  tsum[t] = a + bb;
  __syncthreads();
  for (int off = 1; off < 256; off <<= 1) {
    int v = tsum[t];
    int add = (t >= off) ? tsum[t - off] : 0;
    __syncthreads();
    tsum[t] = v + add;
    __syncthreads();
  }
  const int pre = (t ? tsum[t - 1] : 0) + boff[b];
  if (i0 < len) { row_ptr[s + i0] = pre; cursor[s + i0] = pre; }
  if (i1 < len) { row_ptr[s + i1] = pre + a; cursor[s + i1] = pre + a; }
}

__global__ __launch_bounds__(256) void dinv_k(const int* __restrict__ cnt, float* __restrict__ dinv) {
  int i = blockIdx.x * 256 + threadIdx.x;
  if (i < N_NODES) dinv[i] = rsqrtf((float)cnt[i] + 1.0f);   // deg + self-loop
}

__global__ __launch_bounds__(256) void scatter_k(const int* __restrict__ src, const int* __restrict__ dst,
                                                 int* __restrict__ cursor, int* __restrict__ src_s) {
  int i = blockIdx.x * 256 + threadIdx.x;
  if (i < N_EDGES) {
    int d = dst[i];
    int p = atomicAdd(&cursor[d], 1);
    src_s[p] = src[i];
  }
}

// ---------------- per-layer kernels ----------------

// Y[n] = dinv[n] * (X[n] @ W)   fp32, 32 rows/block, W k-tiled 32x128 in LDS
__global__ __launch_bounds__(256) void gemm_y_k(const float* __restrict__ X, const float* __restrict__ W,
                                                const float* __restrict__ dinv, float* __restrict__ Y) {
  __shared__ float xs[32 * C];   // 16 KB
  __shared__ float ws[32 * C];   // 16 KB (k-tile)
  const int tid = threadIdx.x;
  const int cg = tid & 31;    // cols cg*4 .. cg*4+3
  const int rs = tid >> 5;    // rows rs, rs+8, rs+16, rs+24
  const int row0 = blockIdx.x * 32;
  {
    const float4* X4 = (const float4*)(X + (size_t)row0 * C);
    float4* s4 = (float4*)xs;
#pragma unroll
    for (int i = 0; i < 4; i++) s4[tid + i * 256] = X4[tid + i * 256];
  }
  float4 acc[4];
#pragma unroll
  for (int r = 0; r < 4; r++) acc[r] = make_float4(0.f, 0.f, 0.f, 0.f);
  const float4* xs4 = (const float4*)xs;
  const float4* ws4 = (const float4*)ws;
#pragma unroll
  for (int kt = 0; kt < 4; kt++) {
    __syncthreads();
    {
      const float4* W4 = (const float4*)(W + (size_t)kt * 32 * C);
      float4* s4 = (float4*)ws;
#pragma unroll
      for (int i = 0; i < 4; i++) s4[tid + i * 256] = W4[tid + i * 256];
    }
    __syncthreads();
#pragma unroll
    for (int k4 = 0; k4 < 8; k4++) {
      float4 xv[4];
#pragma unroll
      for (int r = 0; r < 4; r++) xv[r] = xs4[(rs + 8 * r) * 32 + kt * 8 + k4];
#pragma unroll
      for (int j = 0; j < 4; j++) {
        float4 wv = ws4[(k4 * 4 + j) * 32 + cg];
#pragma unroll
        for (int r = 0; r < 4; r++) {
          float xsc = (j == 0) ? xv[r].x : (j == 1) ? xv[r].y : (j == 2) ? xv[r].z : xv[r].w;
          acc[r].x += xsc * wv.x;
          acc[r].y += xsc * wv.y;
          acc[r].z += xsc * wv.z;
          acc[r].w += xsc * wv.w;
        }
      }
    }
  }
#pragma unroll
  for (int r = 0; r < 4; r++) {
    const int row = row0 + rs + 8 * r;
    const float dn = dinv[row];
    float4 o = acc[r];
    o.x *= dn; o.y *= dn; o.z *= dn; o.w *= dn;
    ((float4*)Y)[(size_t)row * 32 + cg] = o;
  }
}

// out[n] = dinv[n]*(Y[n] + sum_{e in CSR[n]} Y[src_e]) + b    (32 lanes per node)
__global__ __launch_bounds__(256) void agg_k(const float* __restrict__ Y, const int* __restrict__ row_ptr,
                                             const int* __restrict__ src_s, const float* __restrict__ dinv,
                                             const float* __restrict__ bias, float* __restrict__ out) {
  const int sub = threadIdx.x >> 5;
  const int lane = threadIdx.x & 31;
  const int n = blockIdx.x * 8 + sub;   // grid is exact: 12500*8 = 100000
  const float4* Y4 = (const float4*)Y;
  float4 acc = Y4[(size_t)n * 32 + lane];
  const int e0 = row_ptr[n];
  const int e1 = row_ptr[n + 1];
  for (int e = e0; e < e1; e++) {
    const int s = src_s[e];
    const float4 v = Y4[(size_t)s * 32 + lane];
    acc.x += v.x; acc.y += v.y; acc.z += v.z; acc.w += v.w;
  }
  const float dn = dinv[n];
  const float4 bb = ((const float4*)bias)[lane];
  float4 o;
  o.x = acc.x * dn + bb.x;
  o.y = acc.y * dn + bb.y;
  o.z = acc.z * dn + bb.z;
  o.w = acc.w * dn + bb.w;
  ((float4*)out)[(size_t)n * 32 + lane] = o;
}

__device__ __forceinline__ void flush4(float* dst, int g, int lane, float4 a) {
  float* p = dst + g * C + lane * 4;
  atomicAdd(p + 0, a.x);
  atomicAdd(p + 1, a.y);
  atomicAdd(p + 2, a.z);
  atomicAdd(p + 3, a.w);
}

// segment-sum of A over sorted batch -> meansum[G][C]; 8 groups/block, 64 nodes/group
__global__ __launch_bounds__(256) void gn_meansum_k(const float* __restrict__ A, const int* __restrict__ batch,
                                                    float* __restrict__ meansum) {
  const int sub = threadIdx.x >> 5;
  const int lane = threadIdx.x & 31;
  const int n0 = (blockIdx.x * 8 + sub) * 64;
  if (n0 >= N_NODES) return;
  const int nend = min(n0 + 64, N_NODES);
  const float4* A4 = (const float4*)A;
  float4 acc = make_float4(0.f, 0.f, 0.f, 0.f);
  int curg = batch[n0];
  for (int n = n0; n < nend; n++) {
    const int g = batch[n];
    if (g != curg) {
      flush4(meansum, curg, lane, acc);
      acc = make_float4(0.f, 0.f, 0.f, 0.f);
      curg = g;
    }
    const float4 v = A4[(size_t)n * 32 + lane];
    acc.x += v.x; acc.y += v.y; acc.z += v.z; acc.w += v.w;
  }
  flush4(meansum, curg, lane, acc);
}

// A <- A - mean[g]*mean_scale (in place), accumulate varsum[G][C]
__global__ __launch_bounds__(256) void gn_center_var_k(float* __restrict__ A, const int* __restrict__ batch,
                                                       const float* __restrict__ meansum,
                                                       const float* __restrict__ cntinv,
                                                       const float* __restrict__ mscale,
                                                       float* __restrict__ varsum) {
  const int sub = threadIdx.x >> 5;
  const int lane = threadIdx.x & 31;
  const int n0 = (blockIdx.x * 8 + sub) * 64;
  if (n0 >= N_NODES) return;
  const int nend = min(n0 + 64, N_NODES);
  float4* A4 = (float4*)A;
  const float4* MS4 = (const float4*)meansum;
  const float4 ms = ((const float4*)mscale)[lane];
  int curg = batch[n0];
  float ci = cntinv[curg];
  float4 msum = MS4[curg * 32 + lane];
  float4 mval = make_float4(msum.x * ci * ms.x, msum.y * ci * ms.y, msum.z * ci * ms.z, msum.w * ci * ms.w);
  float4 acc = make_float4(0.f, 0.f, 0.f, 0.f);
  for (int n = n0; n < nend; n++) {
    const int g = batch[n];
    if (g != curg) {
      flush4(varsum, curg, lane, acc);
      acc = make_float4(0.f, 0.f, 0.f, 0.f);
      curg = g;
      ci = cntinv[g];
      msum = MS4[g * 32 + lane];
      mval = make_float4(msum.x * ci * ms.x, msum.y * ci * ms.y, msum.z * ci * ms.z, msum.w * ci * ms.w);
    }
    float4 v = A4[(size_t)n * 32 + lane];
    v.x -= mval.x; v.y -= mval.y; v.z -= mval.z; v.w -= mval.w;
    A4[(size_t)n * 32 + lane] = v;
    acc.x += v.x * v.x; acc.y += v.y * v.y; acc.z += v.z * v.z; acc.w += v.w * v.w;
  }
  flush4(varsum, curg, lane, acc);
}

// A <- leaky_relu(A * rsqrt(var+eps) * w + b) in place; optional copy to out2
__global__ __launch_bounds__(256) void gn_apply_k(float* __restrict__ A, const int* __restrict__ batch,
                                                  const float* __restrict__ varsum,
                                                  const float* __restrict__ cntinv,
                                                  const float* __restrict__ w, const float* __restrict__ bias,
                                                  float* __restrict__ out2) {
  const int idx = blockIdx.x * 256 + threadIdx.x;   // over N*32 float4, exact grid
  const int n = idx >> 5;
  const int lane = idx & 31;
  const int g = batch[n];
  const float ci = cntinv[g];
  const float4 vs = ((const float4*)varsum)[g * 32 + lane];
  const float4 wv = ((const float4*)w)[lane];
  const float4 bv = ((const float4*)bias)[lane];
  float4 v = ((const float4*)A)[idx];
  float r;
  r = rsqrtf(vs.x * ci + EPS); v.x = v.x * r * wv.x + bv.x; v.x = (v.x > 0.f) ? v.x : SLOPE * v.x;
  r = rsqrtf(vs.y * ci + EPS); v.y = v.y * r * wv.y + bv.y; v.y = (v.y > 0.f) ? v.y : SLOPE * v.y;
  r = rsqrtf(vs.z * ci + EPS); v.z = v.z * r * wv.z + bv.z; v.z = (v.z > 0.f) ? v.z : SLOPE * v.z;
  r = rsqrtf(vs.w * ci + EPS); v.w = v.w * r * wv.w + bv.w; v.w = (v.w > 0.f) ? v.w : SLOPE * v.w;
  ((float4*)A)[idx] = v;
  if (out2) ((float4*)out2)[idx] = v;
}

// ---------------- driver ----------------

extern "C" void kernel_launch(void* const* d_in, const int* in_sizes, int n_in,
                              void* d_out, int out_size, void* d_ws, size_t ws_size,
                              hipStream_t stream) {
  const float* x = (const float*)d_in[0];
  const int* ei = (const int*)d_in[1];
  const int* batch = (const int*)d_in[2];
  const float* W = (const float*)d_in[3];
  const float* b = (const float*)d_in[4];
  const float* gw = (const float*)d_in[5];
  const float* gb = (const float*)d_in[6];
  const float* gms = (const float*)d_in[7];
  float* out = (float*)d_out;

  const int* src = ei;
  const int* dst = ei + N_EDGES;

  // workspace layout (all chunks multiple-of-4 elements -> 16B aligned)
  float* y = (float*)d_ws;                          // N*C
  int* cnt = (int*)(y + (size_t)N_NODES * C);       // N
  int* row_ptr = cnt + N_NODES;                     // N+4
  int* cursor = row_ptr + N_NODES + 4;              // N
  int* src_s = cursor + N_NODES;                    // E
  float* dinv = (float*)(src_s + N_EDGES);          // N
  float* cntinv = dinv + N_NODES;                   // G
  float* meansum = cntinv + G;                      // G*C
  float* varsum = meansum + G * C;                  // G*C
  int* bsum = (int*)(varsum + G * C);               // 256
  int* boff = bsum + 256;                           // 256

  hipMemsetAsync(cnt, 0, N_NODES * sizeof(int), stream);
  hist_edges_k<<<(N_EDGES + 255) / 256, 256, 0, stream>>>(dst, cnt);
  graph_cnt_k<<<1, 64, 0, stream>>>(batch, cntinv);
  scan1_k<<<SCAN_BLOCKS, 256, 0, stream>>>(cnt, bsum);
  scan2_k<<<1, 256, 0, stream>>>(bsum, boff, row_ptr);
  scan3_k<<<SCAN_BLOCKS, 256, 0, stream>>>(cnt, boff, row_ptr, cursor);
  dinv_k<<<(N_NODES + 255) / 256, 256, 0, stream>>>(cnt, dinv);
  scatter_k<<<(N_EDGES + 255) / 256, 256, 0, stream>>>(src, dst, cursor, src_s);

  for (int l = 0; l < NL; l++) {
    const float* Xl = (l == 0) ? x : out + (size_t)N_NODES * C * l;  // previous history slot
    float* slot = out + (size_t)N_NODES * C * (1 + l);
    hipMemsetAsync(meansum, 0, 2 * G * C * sizeof(float), stream);   // meansum+varsum adjacent
    gemm_y_k<<<N_NODES / 32, 256, 0, stream>>>(Xl, W + (size_t)l * C * C, dinv, y);
    agg_k<<<N_NODES / 8, 256, 0, stream>>>(y, row_ptr, src_s, dinv, b + (size_t)l * C, slot);
    gn_meansum_k<<<(N_NODES + 511) / 512, 256, 0, stream>>>(slot, batch, meansum);
    gn_center_var_k<<<(N_NODES + 511) / 512, 256, 0, stream>>>(slot, batch, meansum, cntinv,
                                                               gms + (size_t)l * C, varsum);
    gn_apply_k<<<(N_NODES * 32) / 256, 256, 0, stream>>>(slot, batch, varsum, cntinv,
                                                         gw + (size_t)l * C, gb + (size_t)l * C,
                                                         (l == NL - 1) ? out : nullptr);
  }
}